// Round 1
// 154.603 us; speedup vs baseline: 1.0110x; 1.0110x over previous
//
#include <hip/hip_runtime.h>
#include <math.h>

// loss = ALPHA * mean(level_w * (softplus(x) - x*t))
//      + BETA  * sum_{b,e} relu(sig(x[b,dst]) - sig(x[b,src])) / (B*N)
//
// R6: persistent software-pipelined blocks. grid=256 (1 block/CU), 1024
// threads, 4 row-groups per block, double-buffered P (2x32 KB LDS).
// Per group-iteration: issue next group's global loads into registers,
// run edge gathers on current P buffer (LDS work hides HBM latency),
// then transform the landed registers into the other buffer. One barrier
// per group. Edge indices hoisted into registers once per block.

#define ALPHA_C 1.0f
#define BETA_C  0.5f

constexpr int B = 4096;
constexpr int N = 4096;
constexpr int E = 16384;
constexpr int THREADS = 1024;
constexpr int R = 4;            // rows per group
constexpr int GRID = 256;       // 1 block/CU
constexpr int GPB = (B / R) / GRID;     // 4 groups per block
constexpr int EJ = E / 4 / THREADS;     // 4 edge-iters per thread

typedef _Float16 h4 __attribute__((ext_vector_type(4)));

__global__ __launch_bounds__(64) void init_out_kernel(float* out) {
    if (threadIdx.x == 0) out[0] = 0.0f;
}

__device__ __forceinline__ void fast_sig_sp(float x, float& p, float& sp) {
    // q = exp(-|x|) in (0,1]; both sigmoid and softplus from one exp
    float q = __expf(-fabsf(x));
    float d = 1.0f + q;
    float r = __builtin_amdgcn_rcpf(d);     // ~1 ulp approx reciprocal
    p  = (x >= 0.0f) ? r : q * r;           // sigmoid
    sp = fmaxf(x, 0.0f) + __logf(d);        // softplus = max(x,0)+log(1+q)
}

__global__ __launch_bounds__(THREADS, 4) void hier_loss_kernel(
    const float* __restrict__ outputs,
    const float* __restrict__ targets,
    const float* __restrict__ level_w,
    const int*   __restrict__ edge_src,
    const int*   __restrict__ edge_dst,
    float*       __restrict__ out)
{
    __shared__ h4 P[2][N];          // 64 KB, double-buffered fp16 sigmoid rows

    const int tid = threadIdx.x;
    const int g0  = blockIdx.x * GPB;   // first row-group of this block

    const float4* out4 = (const float4*)outputs;
    const float4* tgt4 = (const float4*)targets;
    const float4* lw4  = (const float4*)level_w;
    const int4*   es4  = (const int4*)edge_src;
    const int4*   ed4  = (const int4*)edge_dst;

    // level weights: this thread's float4-column, constant across groups
    const float4 w = lw4[tid];
    const float wv[4] = {w.x, w.y, w.z, w.w};

    // edge indices: load once, reuse for all GPB groups (32 VGPRs)
    int4 se[EJ], de[EJ];
#pragma unroll
    for (int j = 0; j < EJ; ++j) {
        se[j] = es4[tid + j * THREADS];
        de[j] = ed4[tid + j * THREADS];
    }

    float s1 = 0.0f, s2 = 0.0f;
    float4 xs[R], ts[R];

    // ---- prologue: load + transform group g0 into P[0] ----
#pragma unroll
    for (int r = 0; r < R; ++r) {
        const size_t row = (size_t)((g0 + 0) * R + r) * (N / 4) + tid;
        xs[r] = out4[row];
        ts[r] = tgt4[row];
    }
    {
        h4 tmp[4];
#pragma unroll
        for (int r = 0; r < R; ++r) {
            const float xv[4] = {xs[r].x, xs[r].y, xs[r].z, xs[r].w};
            const float tv[4] = {ts[r].x, ts[r].y, ts[r].z, ts[r].w};
#pragma unroll
            for (int k = 0; k < 4; ++k) {
                float p, sp;
                fast_sig_sp(xv[k], p, sp);
                s1 = fmaf(wv[k], sp - xv[k] * tv[k], s1);
                tmp[k][r] = (_Float16)p;
            }
        }
#pragma unroll
        for (int k = 0; k < 4; ++k) P[0][4 * tid + k] = tmp[k];
    }
    __syncthreads();

    // ---- pipelined main loop: edges(g) overlap loads(g+1) ----
#pragma unroll
    for (int kg = 0; kg < GPB; ++kg) {
        // issue next group's global loads early; latency hidden by edge phase
        if (kg + 1 < GPB) {
#pragma unroll
            for (int r = 0; r < R; ++r) {
                const size_t row = (size_t)((g0 + kg + 1) * R + r) * (N / 4) + tid;
                xs[r] = out4[row];
                ts[r] = tgt4[row];
            }
        }

        // edge consistency on current buffer; one b64 gather covers 4 rows
        const h4* Pc = P[kg & 1];
        h4 acc0 = {0, 0, 0, 0};
        h4 acc1 = {0, 0, 0, 0};
        const h4 zero = {0, 0, 0, 0};
#pragma unroll
        for (int j = 0; j < EJ; ++j) {
            const int4 s = se[j];
            const int4 d = de[j];
            h4 a0 = Pc[s.x], c0 = Pc[d.x];
            h4 a1 = Pc[s.y], c1 = Pc[d.y];
            h4 a2 = Pc[s.z], c2 = Pc[d.z];
            h4 a3 = Pc[s.w], c3 = Pc[d.w];
            acc0 += __builtin_elementwise_max(c0 - a0, zero);   // v_pk_* fp16
            acc1 += __builtin_elementwise_max(c1 - a1, zero);
            acc0 += __builtin_elementwise_max(c2 - a2, zero);
            acc1 += __builtin_elementwise_max(c3 - a3, zero);
        }
#pragma unroll
        for (int l = 0; l < 4; ++l) s2 += (float)acc0[l] + (float)acc1[l];

        // transform next group's landed registers into the other buffer
        if (kg + 1 < GPB) {
            h4 tmp[4];
#pragma unroll
            for (int r = 0; r < R; ++r) {
                const float xv[4] = {xs[r].x, xs[r].y, xs[r].z, xs[r].w};
                const float tv[4] = {ts[r].x, ts[r].y, ts[r].z, ts[r].w};
#pragma unroll
                for (int k = 0; k < 4; ++k) {
                    float p, sp;
                    fast_sig_sp(xv[k], p, sp);
                    s1 = fmaf(wv[k], sp - xv[k] * tv[k], s1);
                    tmp[k][r] = (_Float16)p;
                }
            }
#pragma unroll
            for (int k = 0; k < 4; ++k) P[(kg + 1) & 1][4 * tid + k] = tmp[k];
        }
        __syncthreads();   // P[kg&1] reads done; P[(kg+1)&1] writes visible
    }

    // ---- block reduce: wave64 shuffle, cross-wave via reused LDS ----
#pragma unroll
    for (int off = 32; off > 0; off >>= 1) {
        s1 += __shfl_down(s1, off, 64);
        s2 += __shfl_down(s2, off, 64);
    }
    float* red = (float*)P;              // safe after final loop barrier
    const int wave = tid >> 6;           // 16 waves
    const int lane = tid & 63;
    if (lane == 0) { red[wave] = s1; red[16 + wave] = s2; }
    __syncthreads();
    if (tid == 0) {
        float a = 0.0f, c = 0.0f;
#pragma unroll
        for (int v = 0; v < 16; ++v) { a += red[v]; c += red[16 + v]; }
        const float inv = 1.0f / ((float)B * (float)N);
        atomicAdd(out, (ALPHA_C * a + BETA_C * c) * inv);
    }
}

extern "C" void kernel_launch(void* const* d_in, const int* in_sizes, int n_in,
                              void* d_out, int out_size, void* d_ws, size_t ws_size,
                              hipStream_t stream) {
    const float* outputs = (const float*)d_in[0];
    const float* targets = (const float*)d_in[1];
    const float* level_w = (const float*)d_in[2];
    const int*   edge_src = (const int*)d_in[3];
    const int*   edge_dst = (const int*)d_in[4];
    float* out = (float*)d_out;

    init_out_kernel<<<1, 64, 0, stream>>>(out);
    hier_loss_kernel<<<GRID, THREADS, 0, stream>>>(outputs, targets, level_w,
                                                   edge_src, edge_dst, out);
}